// Round 3
// baseline (431.753 us; speedup 1.0000x reference)
//
#include <hip/hip_runtime.h>
#include <hip/hip_bf16.h>
#include <stdint.h>

// Problem constants
#define H2      1024
#define SEQ     512
#define BATCH   64
#define M_TOTAL (SEQ * BATCH)   // 32768 rows, row m = s*64 + b (enc layout (S,B,H2))

typedef __attribute__((ext_vector_type(8))) short short8;  // 8 bf16 (4 VGPRs)
typedef __attribute__((ext_vector_type(4))) float f32x4;   // mfma acc

__device__ __forceinline__ unsigned pack2_bf16(float lo, float hi) {
    union { __hip_bfloat162 h; unsigned u; } v;
    v.h = __float22bfloat162_rn(make_float2(lo, hi));
    return v.u;
}

__device__ __forceinline__ float fast_tanh(float x) {
    float e = __expf(2.0f * x);
    return __fdividef(e - 1.0f, e + 1.0f);
}

// Async global->LDS, 16B per lane; LDS dest = wave-uniform base + lane*16.
__device__ __forceinline__ void gl_lds16(const unsigned short* g, unsigned short* l) {
    __builtin_amdgcn_global_load_lds(
        (const __attribute__((address_space(1))) unsigned int*)g,
        (__attribute__((address_space(3))) unsigned int*)l, 16, 0, 0);
}

// ------------------------------------------------------------------
// Kernel 1a: W1 enc-slice -> bf16 K-major; also: logits = 0, sp = b1 (bias preload).
__global__ __launch_bounds__(256) void k_prep(const float* __restrict__ W1,
                                              const float* __restrict__ b1,
                                              unsigned short* __restrict__ W1e,
                                              float* __restrict__ logits,
                                              float* __restrict__ sp) {
    int blk = blockIdx.x, tid = threadIdx.x;
    int i = blk * 256 + tid;                    // 1024 blocks
    int e = i << 2;
    int h = e >> 10, k = e & 1023;
    float4 v = *(const float4*)(W1 + (size_t)h * 3072 + 2048 + k);
    uint2 o;
    o.x = pack2_bf16(v.x, v.y);
    o.y = pack2_bf16(v.z, v.w);
    *(uint2*)(W1e + ((size_t)h << 10) + k) = o;
    if (blk < 128) {
        logits[i] = 0.f;                        // 128*256 = 32768
    } else if (blk < 384) {
        int j = i - 32768;                      // 256*256 = 65536
        sp[j] = b1[j & 1023];
    }
}

// Kernel 1b: enc fp32 -> bf16, same (m = s*64+b, k) layout.
__global__ __launch_bounds__(256) void k_prep_enc(const float* __restrict__ enc,
                                                  unsigned short* __restrict__ encb) {
    size_t i = ((size_t)blockIdx.x * 256 + threadIdx.x) << 3;  // 8 elems/thread
    float4 v0 = *(const float4*)(enc + i);
    float4 v1 = *(const float4*)(enc + i + 4);
    uint4 o;
    o.x = pack2_bf16(v0.x, v0.y); o.y = pack2_bf16(v0.z, v0.w);
    o.z = pack2_bf16(v1.x, v1.y); o.w = pack2_bf16(v1.z, v1.w);
    *(uint4*)(encb + i) = o;
}

// ------------------------------------------------------------------
// Kernel 2: sp[b][h] += sum_k state-slice; 128 blocks (mT 0..63 x layer 0..1).
__global__ __launch_bounds__(256) void k_stateproj(const float* __restrict__ W1,
                                                   const float* __restrict__ state,
                                                   float* __restrict__ sp) {
    int lane = threadIdx.x & 63;
    int wave = threadIdx.x >> 6;        // b-tile 0..3
    int blk  = blockIdx.x;              // 128
    int mT   = blk >> 1, l = blk & 1;
    int c    = lane & 15;
    int kq   = (lane >> 4) << 3;        // 0,8,16,24
    int h    = mT * 16 + c;
    int b    = wave * 16 + c;
    const float* ap = W1 + (size_t)h * 3072 + l * 1024 + kq;
    const float* bp = state + (((size_t)l * 64 + b) << 10) + kq;
    f32x4 acc = {0.f, 0.f, 0.f, 0.f};
    #pragma unroll 4
    for (int k0 = 0; k0 < 1024; k0 += 32) {
        float4 a0 = *(const float4*)(ap + k0);
        float4 a1 = *(const float4*)(ap + k0 + 4);
        float4 b0 = *(const float4*)(bp + k0);
        float4 b1v = *(const float4*)(bp + k0 + 4);
        union { short8 s; uint4 u; } fa, fb;
        fa.u.x = pack2_bf16(a0.x, a0.y); fa.u.y = pack2_bf16(a0.z, a0.w);
        fa.u.z = pack2_bf16(a1.x, a1.y); fa.u.w = pack2_bf16(a1.z, a1.w);
        fb.u.x = pack2_bf16(b0.x, b0.y); fb.u.y = pack2_bf16(b0.z, b0.w);
        fb.u.z = pack2_bf16(b1v.x, b1v.y); fb.u.w = pack2_bf16(b1v.z, b1v.w);
        acc = __builtin_amdgcn_mfma_f32_16x16x32_bf16(fa.s, fb.s, acc, 0, 0, 0);
    }
    int quad = lane >> 4;
    int bcol = wave * 16 + c;
    #pragma unroll
    for (int i = 0; i < 4; ++i)
        atomicAdd(&sp[((size_t)bcol << 10) + mT * 16 + quad * 4 + i], acc[i]);
}

// ------------------------------------------------------------------
// Kernel 3: C(32768,1024) = encb @ W1e^T, fused tanh/W2/reduce epilogue.
// LDS layout is MFMA-native: region r (1KB) = 16-row block B=(r>>1), k-sub s=(r&1);
// element for lane L of the consuming ds_read_b128 sits at r*1024B + L*16B ->
// fragment reads are stride-1 across lanes = zero bank conflicts, and the
// glds staging writes exactly that (wave-uniform base + lane*16B).
#define BM 128
#define BN 128
#define BK 64

__global__ __launch_bounds__(256, 3) void k_energy(const unsigned short* __restrict__ encb,
                                                   const unsigned short* __restrict__ W1e,
                                                   const float* __restrict__ sp,
                                                   const float* __restrict__ W2,
                                                   float* __restrict__ logits) {
    __shared__ unsigned short As[BM * BK];   // 16 KB
    __shared__ unsigned short Bs[BN * BK];   // 16 KB
    int bid = blockIdx.x;
    int c8  = bid & 7;                // XCD id (round-robin dispatch)
    int jj  = bid >> 3;
    int mT  = c8 * 32 + (jj >> 3);    // same-mT blocks share c8 -> same XCD L2
    int nT  = jj & 7;
    int m0  = mT * BM, n0 = nT * BN;
    int tid  = threadIdx.x;
    int lane = tid & 63, wave = tid >> 6;
    int wm   = (wave >> 1) << 6;
    int wn   = (wave & 1) << 6;

    int rowl = lane & 15;     // row within 16-row block (= MFMA m/n index)
    int q    = lane >> 4;     // k-chunk 0..3 (= MFMA k-quad)

    // staging: wave handles regions wave*4+j for both A and B
    const unsigned short* gA[4];
    const unsigned short* gB[4];
    unsigned short* lA[4];
    unsigned short* lB[4];
    #pragma unroll
    for (int j = 0; j < 4; ++j) {
        int r   = wave * 4 + j;
        int Bb  = r >> 1, ssub = r & 1;
        int kof = ssub * 32 + q * 8;
        gA[j] = encb + (size_t)(m0 + Bb * 16 + rowl) * H2 + kof;
        gB[j] = W1e  + (size_t)(n0 + Bb * 16 + rowl) * H2 + kof;
        lA[j] = As + r * 512 + lane * 8;
        lB[j] = Bs + r * 512 + lane * 8;
    }

    f32x4 acc[4][4];
    #pragma unroll
    for (int mi = 0; mi < 4; ++mi)
        #pragma unroll
        for (int ni = 0; ni < 4; ++ni)
            acc[mi][ni] = (f32x4){0.f, 0.f, 0.f, 0.f};

    const unsigned short* afb = As + lane * 8;
    const unsigned short* bfb = Bs + lane * 8;
    int ablk = (wm >> 4) * 2;   // region base for this wave's A rows
    int bblk = (wn >> 4) * 2;

    for (int k0 = 0; k0 < H2; k0 += BK) {
        __syncthreads();                       // prev iter's LDS reads retired
        #pragma unroll
        for (int j = 0; j < 4; ++j) {
            gl_lds16(gA[j] + k0, lA[j]);
            gl_lds16(gB[j] + k0, lB[j]);
        }
        __syncthreads();                       // vmcnt drain -> tiles visible
        #pragma unroll
        for (int s = 0; s < 2; ++s) {
            short8 af[4], bf[4];
            #pragma unroll
            for (int i = 0; i < 4; ++i) {
                af[i] = *(const short8*)(afb + (size_t)(ablk + i * 2 + s) * 512);
                bf[i] = *(const short8*)(bfb + (size_t)(bblk + i * 2 + s) * 512);
            }
            #pragma unroll
            for (int mi = 0; mi < 4; ++mi)
                #pragma unroll
                for (int ni = 0; ni < 4; ++ni)
                    acc[mi][ni] = __builtin_amdgcn_mfma_f32_16x16x32_bf16(af[mi], bf[ni], acc[mi][ni], 0, 0, 0);
        }
    }

    // Epilogue: tanh + W2 dot, quad-shuffle reduce, atomic into logits[b][s]
    int c    = lane & 15;
    int quad = lane >> 4;
    float w2v[4];
    int   hcol[4];
    #pragma unroll
    for (int ni = 0; ni < 4; ++ni) {
        hcol[ni] = n0 + wn + ni * 16 + c;
        w2v[ni]  = W2[hcol[ni]];
    }
    #pragma unroll
    for (int mi = 0; mi < 4; ++mi) {
        #pragma unroll
        for (int i = 0; i < 4; ++i) {
            int m = m0 + wm + mi * 16 + quad * 4 + i;
            int b = m & 63;
            const float* sprow = sp + ((size_t)b << 10);
            float t = 0.f;
            #pragma unroll
            for (int ni = 0; ni < 4; ++ni) {
                float e = acc[mi][ni][i] + sprow[hcol[ni]];
                t = fmaf(fast_tanh(e), w2v[ni], t);
            }
            t += __shfl_xor(t, 1);
            t += __shfl_xor(t, 2);
            t += __shfl_xor(t, 4);
            t += __shfl_xor(t, 8);
            if (c == 0) atomicAdd(logits + (size_t)b * 512 + (m >> 6), t);
        }
    }
}

// Fallback (small ws): fp32 in-loop conversion with padded-LDS staging.
#define LDT 40
__global__ __launch_bounds__(256, 2) void k_energy_f32(const float* __restrict__ enc,
                                                       const unsigned short* __restrict__ W1e,
                                                       const float* __restrict__ sp,
                                                       const float* __restrict__ W2,
                                                       float* __restrict__ logits) {
    __shared__ unsigned short As[BM * LDT];
    __shared__ unsigned short Bs[BN * LDT];
    int bid = blockIdx.x;
    int c8  = bid & 7;
    int jj  = bid >> 3;
    int mT  = c8 * 32 + (jj >> 3);
    int nT  = jj & 7;
    int tid  = threadIdx.x;
    int lane = tid & 63, wave = tid >> 6;
    int wm   = (wave >> 1) << 6;
    int wn   = (wave & 1) << 6;
    int m0   = mT * BM, n0 = nT * BN;

    int arow = tid >> 1;
    int aseg = (tid & 1) << 4;
    const float*          apg = enc + ((size_t)(m0 + arow) << 10) + aseg;
    const unsigned short* wpg = W1e + ((size_t)(n0 + arow) << 10) + aseg;
    unsigned short* asd = As + arow * LDT + aseg;
    unsigned short* bsd = Bs + arow * LDT + aseg;

    f32x4 acc[4][4];
    #pragma unroll
    for (int mi = 0; mi < 4; ++mi)
        #pragma unroll
        for (int ni = 0; ni < 4; ++ni)
            acc[mi][ni] = (f32x4){0.f, 0.f, 0.f, 0.f};

    int c  = lane & 15;
    int kq = (lane >> 4) << 3;
    const unsigned short* afp = As + (wm + c) * LDT + kq;
    const unsigned short* bfp = Bs + (wn + c) * LDT + kq;

    for (int k0 = 0; k0 < 1024; k0 += 32) {
        float4 a0 = *(const float4*)(apg + k0);
        float4 a1 = *(const float4*)(apg + k0 + 4);
        float4 a2 = *(const float4*)(apg + k0 + 8);
        float4 a3 = *(const float4*)(apg + k0 + 12);
        uint4  w0 = *(const uint4*)(wpg + k0);
        uint4  w1 = *(const uint4*)(wpg + k0 + 8);
        uint4 pa0, pa1;
        pa0.x = pack2_bf16(a0.x, a0.y); pa0.y = pack2_bf16(a0.z, a0.w);
        pa0.z = pack2_bf16(a1.x, a1.y); pa0.w = pack2_bf16(a1.z, a1.w);
        pa1.x = pack2_bf16(a2.x, a2.y); pa1.y = pack2_bf16(a2.z, a2.w);
        pa1.z = pack2_bf16(a3.x, a3.y); pa1.w = pack2_bf16(a3.z, a3.w);
        __syncthreads();
        *(uint4*)asd       = pa0;
        *(uint4*)(asd + 8) = pa1;
        *(uint4*)bsd       = w0;
        *(uint4*)(bsd + 8) = w1;
        __syncthreads();
        short8 af[4], bf[4];
        #pragma unroll
        for (int i = 0; i < 4; ++i) {
            af[i] = *(const short8*)(afp + (i << 4) * LDT);
            bf[i] = *(const short8*)(bfp + (i << 4) * LDT);
        }
        #pragma unroll
        for (int mi = 0; mi < 4; ++mi)
            #pragma unroll
            for (int ni = 0; ni < 4; ++ni)
                acc[mi][ni] = __builtin_amdgcn_mfma_f32_16x16x32_bf16(af[mi], bf[ni], acc[mi][ni], 0, 0, 0);
    }

    int quad = lane >> 4;
    float w2v[4];
    int   hcol[4];
    #pragma unroll
    for (int ni = 0; ni < 4; ++ni) {
        hcol[ni] = n0 + wn + ni * 16 + c;
        w2v[ni]  = W2[hcol[ni]];
    }
    #pragma unroll
    for (int mi = 0; mi < 4; ++mi) {
        #pragma unroll
        for (int i = 0; i < 4; ++i) {
            int m = m0 + wm + mi * 16 + quad * 4 + i;
            int b = m & 63;
            const float* sprow = sp + ((size_t)b << 10);
            float t = 0.f;
            #pragma unroll
            for (int ni = 0; ni < 4; ++ni) {
                float e = acc[mi][ni][i] + sprow[hcol[ni]];
                t = fmaf(fast_tanh(e), w2v[ni], t);
            }
            t += __shfl_xor(t, 1);
            t += __shfl_xor(t, 2);
            t += __shfl_xor(t, 4);
            t += __shfl_xor(t, 8);
            if (c == 0) atomicAdd(logits + (size_t)b * 512 + (m >> 6), t);
        }
    }
}

// ------------------------------------------------------------------
// Kernel 4: softmax over s per b; also zeroes ctx (runs before k_context).
__global__ __launch_bounds__(256) void k_softmax(const float* __restrict__ logits,
                                                 float* __restrict__ alpha,
                                                 float* __restrict__ ctx) {
    int b = blockIdx.x;
    int tid = threadIdx.x;
    int lane = tid & 63, wave = tid >> 6;
    #pragma unroll
    for (int j = 0; j < 4; ++j)
        ctx[((size_t)b << 10) + j * 256 + tid] = 0.f;
    float v0 = logits[(size_t)b * 512 + tid];
    float v1 = logits[(size_t)b * 512 + 256 + tid];
    float mx = fmaxf(v0, v1);
    #pragma unroll
    for (int o = 32; o; o >>= 1) mx = fmaxf(mx, __shfl_xor(mx, o));
    __shared__ float redm[4];
    if (lane == 0) redm[wave] = mx;
    __syncthreads();
    mx = fmaxf(fmaxf(redm[0], redm[1]), fmaxf(redm[2], redm[3]));
    float e0 = __expf(v0 - mx), e1 = __expf(v1 - mx);
    float s = e0 + e1;
    #pragma unroll
    for (int o = 32; o; o >>= 1) s += __shfl_xor(s, o);
    __shared__ float reds[4];
    if (lane == 0) reds[wave] = s;
    __syncthreads();
    s = reds[0] + reds[1] + reds[2] + reds[3];
    float inv = 1.0f / s;
    alpha[(size_t)b * 512 + tid]       = e0 * inv;
    alpha[(size_t)b * 512 + 256 + tid] = e1 * inv;
}

// ------------------------------------------------------------------
// Kernel 5: context[b][h] = sum_s alpha[b][s] * enc[s][b][h], fp32.
__global__ __launch_bounds__(256) void k_context(const float* __restrict__ enc,
                                                 const float* __restrict__ alpha,
                                                 float* __restrict__ ctx) {
    int b  = blockIdx.x & 63;
    int sc = blockIdx.x >> 6;
    int h  = threadIdx.x << 2;
    float4 acc = make_float4(0.f, 0.f, 0.f, 0.f);
    int sbase = sc * 64;
    #pragma unroll 4
    for (int si = 0; si < 64; ++si) {
        int s = sbase + si;
        float a = alpha[(size_t)b * 512 + s];
        float4 e = *(const float4*)(enc + (((size_t)s * 64 + b) << 10) + h);
        acc.x = fmaf(a, e.x, acc.x);
        acc.y = fmaf(a, e.y, acc.y);
        acc.z = fmaf(a, e.z, acc.z);
        acc.w = fmaf(a, e.w, acc.w);
    }
    float* dst = ctx + ((size_t)b << 10) + h;
    atomicAdd(dst + 0, acc.x);
    atomicAdd(dst + 1, acc.y);
    atomicAdd(dst + 2, acc.z);
    atomicAdd(dst + 3, acc.w);
}

// ------------------------------------------------------------------
extern "C" void kernel_launch(void* const* d_in, const int* in_sizes, int n_in,
                              void* d_out, int out_size, void* d_ws, size_t ws_size,
                              hipStream_t stream) {
    const float* state = (const float*)d_in[0];   // (2, 64, 1024)
    const float* enc   = (const float*)d_in[1];   // (512, 64, 1024)
    const float* W1    = (const float*)d_in[2];   // (1024, 3072)
    const float* b1    = (const float*)d_in[3];   // (1024,)
    const float* W2    = (const float*)d_in[4];   // (1, 1024)
    // d_in[5] = b2: dropped — softmax is shift-invariant.

    float* ctx   = (float*)d_out;                 // (1,64,1024) = 65536 fp32
    float* alpha = (float*)d_out + 65536;         // (64,1,512)  = 32768 fp32

    char* ws = (char*)d_ws;
    unsigned short* W1e    = (unsigned short*)(ws);             // 2 MB bf16 [h][k]
    float*          sp     = (float*)(ws + 2097152);            // 256 KB [b][h]
    float*          logits = (float*)(ws + 2097152 + 262144);   // 128 KB [b][s]
    unsigned short* encb   = (unsigned short*)(ws + 2097152 + 262144 + 131072); // 64 MB

    const size_t need_full = 2097152 + 262144 + 131072 + (size_t)M_TOTAL * H2 * 2;

    k_prep<<<1024, 256, 0, stream>>>(W1, b1, W1e, logits, sp);
    k_stateproj<<<128, 256, 0, stream>>>(W1, state, sp);
    if (ws_size >= need_full) {
        k_prep_enc<<<16384, 256, 0, stream>>>(enc, encb);
        k_energy<<<M_TOTAL / BM * (H2 / BN), 256, 0, stream>>>(encb, W1e, sp, W2, logits);
    } else {
        k_energy_f32<<<M_TOTAL / BM * (H2 / BN), 256, 0, stream>>>(enc, W1e, sp, W2, logits);
    }
    k_softmax<<<64, 256, 0, stream>>>(logits, alpha, ctx);
    k_context<<<512, 256, 0, stream>>>(enc, alpha, ctx);
}